// Round 3
// baseline (470.245 us; speedup 1.0000x reference)
//
#include <hip/hip_runtime.h>

// LinearAttention (B=16, C=256, 64x64 spatial, 8 heads x 32) -- fp32 in/out, bf16/fp32 internal.
// Workspace map (byte offsets), peak 98 MiB:
//   ctxg  [0, 512K)              fp32 [16][8][32][32]
//   ksumg [512K, 528K)           fp32 [16][8][32]
//   wb    [528K, 1040K)          bf16 weights: wk|wv|wq|wo (4 x 65536 elems)
//   xT    [2 MiB, 34 MiB)        bf16 [16][4096][256]   LN(fmap)*g, transposed
//   kvT   [34 MiB, 98 MiB)       bf16 [16][4096][512]   cols 0..255=k1, 256..511=v1
//   qT    [34 MiB, 66 MiB)       alias (kvT dead after ctx)
//   q'    [66 MiB, 98 MiB)       softmaxed q
//   s     [2 MiB, 34 MiB)        silu(attn out)  (xT dead)
//   y     [66 MiB, 98 MiB)       s @ wo^T        (q' dead)
// Order: memset -> prep -> ln_tin -> gemm(KV) -> ctx -> gemm(Q) -> dwq -> attn -> gemm(O) -> ln_tout

typedef unsigned short u16;
typedef __bf16 bf16x8 __attribute__((ext_vector_type(8)));
typedef float f32x4 __attribute__((ext_vector_type(4)));

#define DEV static __device__ __forceinline__

DEV float b2f(u16 u) { return __uint_as_float(((unsigned int)u) << 16); }
DEV u16 f2bf(float f) {
  unsigned int u = __float_as_uint(f);
  return (u16)((u + 0x7fffu + ((u >> 16) & 1u)) >> 16);  // RNE
}
DEV void gl2lds16(const void* g, void* l) {
  __builtin_amdgcn_global_load_lds((__attribute__((address_space(1))) void*)g,
                                   (__attribute__((address_space(3))) void*)l, 16, 0, 0);
}

// ---------------- prep: fp32 -> bf16 weight conversion ----------------
__global__ __launch_bounds__(256) void prep_kernel(const float* __restrict__ wk,
                                                   const float* __restrict__ wv,
                                                   const float* __restrict__ wq,
                                                   const float* __restrict__ wo,
                                                   u16* __restrict__ wb) {
  const int i = blockIdx.x * 256 + threadIdx.x;  // 0..65535
  const float* src = (blockIdx.y == 0) ? wk : (blockIdx.y == 1) ? wv : (blockIdx.y == 2) ? wq : wo;
  wb[blockIdx.y * 65536 + i] = f2bf(src[i]);
}

// ---------------- K0: channel-LN + transpose in (fp32 -> bf16) ----------------
__global__ __launch_bounds__(256) void ln_tin_kernel(const float* __restrict__ f,
                                                     const float* __restrict__ g,
                                                     u16* __restrict__ xT) {
  __shared__ u16 tile[64 * 258];
  __shared__ float red[2 * 256];
  __shared__ float mu_s[64], inv_s[64];
  const int t = threadIdx.x;
  const int p0 = blockIdx.x * 64;
  const int b = blockIdx.y;
  const long fb = (long)b * 256 * 4096;
  const int p = t & 63, cg = t >> 6;
  float s1 = 0.f, s2 = 0.f;
  for (int pass = 0; pass < 64; ++pass) {
    int c = pass * 4 + cg;
    float v = f[fb + (long)c * 4096 + p0 + p];
    s1 += v; s2 += v * v;
    tile[p * 258 + c] = f2bf(v);
  }
  red[cg * 64 + p] = s1;
  red[256 + cg * 64 + p] = s2;
  __syncthreads();
  if (t < 64) {
    float a1 = red[t] + red[64 + t] + red[128 + t] + red[192 + t];
    float a2 = red[256 + t] + red[320 + t] + red[384 + t] + red[448 + t];
    float mu = a1 * (1.f / 256.f);
    float var = a2 * (1.f / 256.f) - mu * mu;
    mu_s[t] = mu;
    inv_s[t] = 1.0f / sqrtf(var + 1e-5f);
  }
  __syncthreads();
  {
    float gc = g[t];
    for (int pp = 0; pp < 64; ++pp) {
      float v = b2f(tile[pp * 258 + t]);
      xT[((long)b * 4096 + p0 + pp) * 256 + t] = f2bf((v - mu_s[pp]) * inv_s[pp] * gc);
    }
  }
}

// ---------------- GEMM: C[m][n] = sum_k A[m][k]*Bt[n][k] (MFMA 16x16x32, 128x128 tile) ----
__global__ __launch_bounds__(256) void gemm_bt_kernel(
    const u16* __restrict__ A, const u16* __restrict__ B0, const u16* __restrict__ B1,
    u16* __restrict__ Cg, int ldc, long sA, long sC) {
  __shared__ u16 As[128 * 32];
  __shared__ u16 Bs[128 * 32];
  const int t = threadIdx.x;
  const int wave = t >> 6, lane = t & 63, quad = lane >> 4, l16 = lane & 15;
  const int wr = wave >> 1, wc = wave & 1;
  const int m0 = blockIdx.x * 128;
  const int jt = blockIdx.y;
  const int b = blockIdx.z;
  const u16* Ab = A + (long)b * sA + (long)m0 * 256;
  const u16* Bt = (jt < 2 ? B0 : B1) + (jt & 1) * 128 * 256;
  u16* Cb = Cg + (long)b * sC + (long)m0 * ldc + jt * 128;

  const int srow = lane >> 2;        // staging: row within 16-row chunk
  const int scol = (lane & 3) * 8;   // staging: col (elements)
  f32x4 acc[4][4];
#pragma unroll
  for (int i = 0; i < 4; ++i)
#pragma unroll
    for (int j = 0; j < 4; ++j) acc[i][j] = (f32x4){0.f, 0.f, 0.f, 0.f};

  const int aoff = (wr * 64 + l16) * 32 + quad * 8;
  const int boff = (wc * 64 + l16) * 32 + quad * 8;

  for (int ks = 0; ks < 8; ++ks) {
    const int k0 = ks * 32;
    __syncthreads();
    for (int i = wave; i < 8; i += 4) {
      gl2lds16(Ab + (i * 16 + srow) * 256 + k0 + scol, &As[i * 512 + lane * 8]);
      gl2lds16(Bt + (i * 16 + srow) * 256 + k0 + scol, &Bs[i * 512 + lane * 8]);
    }
    __syncthreads();  // compiler drains vmcnt(0) before s_barrier
    bf16x8 af[4], bfr[4];
#pragma unroll
    for (int mt = 0; mt < 4; ++mt) af[mt] = *(const bf16x8*)&As[aoff + mt * 512];
#pragma unroll
    for (int nt = 0; nt < 4; ++nt) bfr[nt] = *(const bf16x8*)&Bs[boff + nt * 512];
#pragma unroll
    for (int mt = 0; mt < 4; ++mt)
#pragma unroll
      for (int nt = 0; nt < 4; ++nt)
        acc[mt][nt] = __builtin_amdgcn_mfma_f32_16x16x32_bf16(af[mt], bfr[nt], acc[mt][nt], 0, 0, 0);
  }
#pragma unroll
  for (int mt = 0; mt < 4; ++mt) {
    const int mbase = wr * 64 + mt * 16 + quad * 4;
#pragma unroll
    for (int nt = 0; nt < 4; ++nt) {
      const int n = wc * 64 + nt * 16 + l16;
#pragma unroll
      for (int r = 0; r < 4; ++r)
        Cb[(long)(mbase + r) * ldc + n] = f2bf(acc[mt][nt][r]);
    }
  }
}

// ---------------- slab loader: 18x18 (halo, zero-pad) x 32 channels ----------------
DEV void load_slab(const u16* __restrict__ base, int stride, u16* __restrict__ slab,
                   int x0, int y0, int t) {
  const int c = t & 31;
  for (int pos = t >> 5; pos < 324; pos += 8) {
    int ix = pos / 18, iy = pos - ix * 18;
    int gx = x0 - 1 + ix, gy = y0 - 1 + iy;
    u16 v = 0;
    if ((unsigned)gx < 64u && (unsigned)gy < 64u)
      v = base[(long)(gx * 64 + gy) * stride + c];
    slab[pos * 33 + c] = v;
  }
}

DEV float conv9(const u16* __restrict__ slab, const float* w, int xi, int yi, int c) {
  float a = 0.f;
#pragma unroll
  for (int dx = 0; dx < 3; ++dx)
#pragma unroll
    for (int dy = 0; dy < 3; ++dy)
      a = fmaf(w[dx * 3 + dy], b2f(slab[((xi + dx) * 18 + (yi + dy)) * 33 + c]), a);
  return a;
}

// ---------------- K2: dwconv(q) + softmax over d + *SCALE ----------------
__global__ __launch_bounds__(256) void dwq_kernel(const u16* __restrict__ qT,
                                                  const float* __restrict__ wdw,
                                                  u16* __restrict__ qp) {
  __shared__ u16 slab[324 * 33];
  __shared__ float q2[256 * 33];
  const int t = threadIdx.x;
  const int tile = blockIdx.x, h = blockIdx.y, b = blockIdx.z;
  const int x0 = (tile & 3) * 16, y0 = (tile >> 2) * 16;
  const int c = t & 31, xr = t >> 5;
  load_slab(qT + (long)b * 4096 * 256 + h * 32, 256, slab, x0, y0, t);
  __syncthreads();
  float w[9];
#pragma unroll
  for (int i = 0; i < 9; ++i) w[i] = wdw[(h * 32 + c) * 9 + i];
  for (int xi = xr * 2; xi < xr * 2 + 2; ++xi)
    for (int yi = 0; yi < 16; ++yi)
      q2[(xi * 16 + yi) * 33 + c] = conv9(slab, w, xi, yi, c);
  __syncthreads();
  {
    const int n = t;
    float v[32];
    float m = -1e30f;
#pragma unroll
    for (int d = 0; d < 32; ++d) { v[d] = q2[n * 33 + d]; m = fmaxf(m, v[d]); }
    float s = 0.f;
#pragma unroll
    for (int d = 0; d < 32; ++d) { v[d] = __expf(v[d] - m); s += v[d]; }
    const float inv = 0.17677669529663687f / s;  // SCALE / sum
    const long ob = ((long)b * 4096 + (long)(x0 + (n >> 4)) * 64 + y0 + (n & 15)) * 256 + h * 32;
#pragma unroll
    for (int gq = 0; gq < 4; ++gq) {
      uint4 pk;
      unsigned int* pw = (unsigned int*)&pk;
#pragma unroll
      for (int q2i = 0; q2i < 4; ++q2i) {
        int d = gq * 8 + q2i * 2;
        pw[q2i] = (unsigned)f2bf(v[d] * inv) | ((unsigned)f2bf(v[d + 1] * inv) << 16);
      }
      *(uint4*)(qp + ob + gq * 8) = pk;
    }
  }
}

// ---------------- K3: dwconv(k,v) + exp + Gram via MFMA + atomics ----------------
__global__ __launch_bounds__(256) void ctx_kernel(const u16* __restrict__ kvT,
                                                  const float* __restrict__ wkdw,
                                                  const float* __restrict__ wvdw,
                                                  float* __restrict__ ctxg,
                                                  float* __restrict__ ksumg) {
  __shared__ u16 slab[324 * 33];
  __shared__ u16 ekT[32 * 264];
  __shared__ u16 vT[32 * 264];
  __shared__ float red[8 * 32];
  const int t = threadIdx.x;
  const int tile = blockIdx.x, h = blockIdx.y, b = blockIdx.z;
  const int x0 = (tile & 3) * 16, y0 = (tile >> 2) * 16;
  const int c = t & 31, xr = t >> 5;
  // K  (cols 0..255 of kvT)
  load_slab(kvT + (long)b * 4096 * 512 + h * 32, 512, slab, x0, y0, t);
  __syncthreads();
  {
    float w[9];
#pragma unroll
    for (int i = 0; i < 9; ++i) w[i] = wkdw[(h * 32 + c) * 9 + i];
    for (int xi = xr * 2; xi < xr * 2 + 2; ++xi)
      for (int yi = 0; yi < 16; ++yi)
        ekT[c * 264 + xi * 16 + yi] = f2bf(__expf(conv9(slab, w, xi, yi, c)));
  }
  __syncthreads();
  {  // ksum partials (bf16-rounded ek, consistent with MFMA numerator)
    float s = 0.f;
    for (int k = 0; k < 32; ++k) s += b2f(ekT[c * 264 + xr * 32 + k]);
    red[xr * 32 + c] = s;
  }
  // V  (cols 256..511 of kvT; reuse slab)
  load_slab(kvT + (long)b * 4096 * 512 + 256 + h * 32, 512, slab, x0, y0, t);
  __syncthreads();
  {
    float w[9];
#pragma unroll
    for (int i = 0; i < 9; ++i) w[i] = wvdw[(h * 32 + c) * 9 + i];
    for (int xi = xr * 2; xi < xr * 2 + 2; ++xi)
      for (int yi = 0; yi < 16; ++yi)
        vT[c * 264 + xi * 16 + yi] = f2bf(conv9(slab, w, xi, yi, c));
  }
  __syncthreads();
  if (t < 32) {
    float s = 0.f;
#pragma unroll
    for (int pt = 0; pt < 8; ++pt) s += red[pt * 32 + t];
    atomicAdd(&ksumg[((long)b * 8 + h) * 32 + t], s);
  }
  if (t < 64) {  // wave 0: ctx[d][e] += sum_n ek[d][n]*v[e][n]
    const int lane = t, quad = lane >> 4, l16 = lane & 15;
    float* cbase = ctxg + ((long)b * 8 + h) * 1024;
#pragma unroll
    for (int dt = 0; dt < 2; ++dt)
#pragma unroll
      for (int et = 0; et < 2; ++et) {
        f32x4 acc = (f32x4){0.f, 0.f, 0.f, 0.f};
#pragma unroll
        for (int ks = 0; ks < 8; ++ks) {
          bf16x8 af = *(const bf16x8*)&ekT[(dt * 16 + l16) * 264 + ks * 32 + quad * 8];
          bf16x8 bf_ = *(const bf16x8*)&vT[(et * 16 + l16) * 264 + ks * 32 + quad * 8];
          acc = __builtin_amdgcn_mfma_f32_16x16x32_bf16(af, bf_, acc, 0, 0, 0);
        }
#pragma unroll
        for (int r = 0; r < 4; ++r)
          atomicAdd(&cbase[(dt * 16 + quad * 4 + r) * 32 + et * 16 + l16], acc[r]);
      }
  }
}

// ---------------- K4: s = silu(q' @ (ctx/ksum)) ----------------
__global__ __launch_bounds__(256) void attn_kernel(const u16* __restrict__ qp,
                                                   const float* __restrict__ ctxg,
                                                   const float* __restrict__ ksumg,
                                                   u16* __restrict__ sout) {
  __shared__ float ctxn[8192];
  __shared__ u16 qlds[64 * 40];
  const int t = threadIdx.x;
  const int p0 = blockIdx.x * 64;
  const int b = blockIdx.y;
  for (int i = 0; i < 32; ++i) {
    int idx = i * 256 + t;
    ctxn[idx] = ctxg[(long)b * 8192 + idx] / ksumg[(long)b * 256 + (idx >> 5)];
  }
  __syncthreads();
  const int e = t & 31, pg = t >> 5;
  const int lr = t >> 2, lc = t & 3;
  float cc[32];
  for (int h = 0; h < 8; ++h) {
    __syncthreads();
    *(uint4*)&qlds[lr * 40 + lc * 8] =
        *(const uint4*)&qp[((long)b * 4096 + p0 + lr) * 256 + h * 32 + lc * 8];
#pragma unroll
    for (int d = 0; d < 32; ++d) cc[d] = ctxn[(h * 32 + d) * 32 + e];
    __syncthreads();
    for (int k = 0; k < 8; ++k) {
      int p = pg + k * 8;
      float a = 0.f;
#pragma unroll
      for (int jq = 0; jq < 4; ++jq) {
        bf16x8 qv = *(const bf16x8*)&qlds[p * 40 + jq * 8];
#pragma unroll
        for (int jj = 0; jj < 8; ++jj) a = fmaf((float)qv[jj], cc[jq * 8 + jj], a);
      }
      float sl = a / (1.f + __expf(-a));  // silu
      sout[((long)b * 4096 + p0 + p) * 256 + h * 32 + e] = f2bf(sl);
    }
  }
}

// ---------------- K6: channel-LN + transpose out (bf16 -> fp32) ----------------
__global__ __launch_bounds__(256) void ln_tout_kernel(const u16* __restrict__ y,
                                                      const float* __restrict__ gout,
                                                      float* __restrict__ out) {
  __shared__ u16 tile[64 * 258];
  __shared__ float red[2 * 256];
  __shared__ float mu_s[64], inv_s[64];
  const int t = threadIdx.x;
  const int p0 = blockIdx.x * 64;
  const int b = blockIdx.y;
  for (int p = 0; p < 64; ++p)
    tile[p * 258 + t] = y[((long)b * 4096 + p0 + p) * 256 + t];
  __syncthreads();
  {
    const int p = t & 63, part = t >> 6;
    float s1 = 0.f, s2 = 0.f;
    for (int k = 0; k < 64; ++k) {
      float v = b2f(tile[p * 258 + part * 64 + k]);
      s1 += v; s2 += v * v;
    }
    red[part * 64 + p] = s1;
    red[256 + part * 64 + p] = s2;
  }
  __syncthreads();
  if (t < 64) {
    float s1 = red[t] + red[64 + t] + red[128 + t] + red[192 + t];
    float s2 = red[256 + t] + red[320 + t] + red[384 + t] + red[448 + t];
    float mu = s1 * (1.f / 256.f);
    float var = s2 * (1.f / 256.f) - mu * mu;
    mu_s[t] = mu;
    inv_s[t] = 1.0f / sqrtf(var + 1e-5f);
  }
  __syncthreads();
  {
    const int p = t & 63, cg = t >> 6;
    const long ob = (long)b * 256 * 4096;
    for (int pass = 0; pass < 64; ++pass) {
      int c = pass * 4 + cg;
      float v = b2f(tile[p * 258 + c]);
      out[ob + (long)c * 4096 + p0 + p] = (v - mu_s[p]) * inv_s[p] * gout[c];
    }
  }
}

extern "C" void kernel_launch(void* const* d_in, const int* in_sizes, int n_in,
                              void* d_out, int out_size, void* d_ws, size_t ws_size,
                              hipStream_t stream) {
  (void)in_sizes; (void)n_in; (void)out_size; (void)ws_size;
  const float* fmap = (const float*)d_in[0];
  const float* gnorm = (const float*)d_in[1];
  const float* wq1 = (const float*)d_in[2];
  const float* wqdw = (const float*)d_in[3];
  const float* wk1 = (const float*)d_in[4];
  const float* wkdw = (const float*)d_in[5];
  const float* wv1 = (const float*)d_in[6];
  const float* wvdw = (const float*)d_in[7];
  const float* wo = (const float*)d_in[8];
  const float* gout = (const float*)d_in[9];
  float* out = (float*)d_out;
  char* ws = (char*)d_ws;

  float* ctxg = (float*)(ws);                    // [0, 512K)
  float* ksumg = (float*)(ws + 524288);          // [512K, 528K)
  u16* wb = (u16*)(ws + 540672);                 // [528K, 1040K) bf16 wk|wv|wq|wo
  u16* wk_bf = wb;
  u16* wv_bf = wb + 65536;
  u16* wq_bf = wb + 131072;
  u16* wo_bf = wb + 196608;
  u16* xT = (u16*)(ws + 2097152);                // [2, 34) MiB
  u16* kvT = (u16*)(ws + 35651584);              // [34, 98) MiB
  u16* qT = kvT;                                 // alias (kvT dead after ctx)
  u16* qp = (u16*)(ws + 69206016);               // [66, 98) MiB
  u16* sbuf = xT;                                // alias (xT dead after Q gemm)
  u16* ybuf = qp;                                // alias (qp dead after attn)

  hipMemsetAsync(ws, 0, 540672, stream);
  prep_kernel<<<dim3(256, 4), 256, 0, stream>>>(wk1, wv1, wq1, wo, wb);
  ln_tin_kernel<<<dim3(64, 16), 256, 0, stream>>>(fmap, gnorm, xT);
  // KV: cols 0..255 = x@wk1^T, cols 256..511 = x@wv1^T
  gemm_bt_kernel<<<dim3(32, 4, 16), 256, 0, stream>>>(xT, wk_bf, wv_bf, kvT, 512,
                                                      4096L * 256, 4096L * 512);
  ctx_kernel<<<dim3(16, 8, 16), 256, 0, stream>>>(kvT, wkdw, wvdw, ctxg, ksumg);
  // Q
  gemm_bt_kernel<<<dim3(32, 2, 16), 256, 0, stream>>>(xT, wq_bf, wq_bf, qT, 256,
                                                      4096L * 256, 4096L * 256);
  dwq_kernel<<<dim3(16, 8, 16), 256, 0, stream>>>(qT, wqdw, qp);
  attn_kernel<<<dim3(64, 16), 256, 0, stream>>>(qp, ctxg, ksumg, sbuf);
  // O
  gemm_bt_kernel<<<dim3(32, 2, 16), 256, 0, stream>>>(sbuf, wo_bf, wo_bf, ybuf, 256,
                                                      4096L * 256, 4096L * 256);
  ln_tout_kernel<<<dim3(64, 16), 256, 0, stream>>>(ybuf, gout, out);
}

// Round 4
// 380.932 us; speedup vs baseline: 1.2345x; 1.2345x over previous
//
#include <hip/hip_runtime.h>

// LinearAttention (B=16, C=256, 64x64 spatial, 8 heads x 32) -- fp32 in/out, bf16/fp32 internal.
// Workspace map (byte offsets), peak 98 MiB:
//   ctxg  [0, 512K)              fp32 [16][8][32][32]
//   ksumg [512K, 528K)           fp32 [16][8][32]
//   wb    [528K, 1040K)          bf16 weights: wk|wv|wq|wo (4 x 65536 elems)
//   xT    [2 MiB, 34 MiB)        bf16 [16][4096][256]   LN(fmap)*g, transposed
//   kvT   [34 MiB, 98 MiB)       bf16 [16][4096][512]   cols 0..255=k1, 256..511=v1
//   qT    [34 MiB, 66 MiB)       alias (kvT dead after ctx)
//   q'    [66 MiB, 98 MiB)       softmaxed q
//   s     [2 MiB, 34 MiB)        silu(attn out)  (xT dead)
//   y     [66 MiB, 98 MiB)       s @ wo^T        (q' dead)
// Order: memset -> prep -> ln_tin -> gemm(KV) -> ctx -> gemm(Q) -> dwq -> attn -> gemm(O) -> ln_tout

typedef unsigned short u16;
typedef __bf16 bf16x8 __attribute__((ext_vector_type(8)));
typedef float f32x4 __attribute__((ext_vector_type(4)));
typedef float f32x16 __attribute__((ext_vector_type(16)));

#define DEV static __device__ __forceinline__

DEV float b2f(u16 u) { return __uint_as_float(((unsigned int)u) << 16); }
DEV u16 f2bf(float f) {
  unsigned int u = __float_as_uint(f);
  return (u16)((u + 0x7fffu + ((u >> 16) & 1u)) >> 16);  // RNE
}
DEV void gl2lds16(const void* g, void* l) {
  __builtin_amdgcn_global_load_lds((__attribute__((address_space(1))) void*)g,
                                   (__attribute__((address_space(3))) void*)l, 16, 0, 0);
}

// ---------------- prep: fp32 -> bf16 weight conversion ----------------
__global__ __launch_bounds__(256) void prep_kernel(const float* __restrict__ wk,
                                                   const float* __restrict__ wv,
                                                   const float* __restrict__ wq,
                                                   const float* __restrict__ wo,
                                                   u16* __restrict__ wb) {
  const int i = blockIdx.x * 256 + threadIdx.x;  // 0..65535
  const float* src = (blockIdx.y == 0) ? wk : (blockIdx.y == 1) ? wv : (blockIdx.y == 2) ? wq : wo;
  wb[blockIdx.y * 65536 + i] = f2bf(src[i]);
}

// ---------------- K0: channel-LN + transpose in (fp32 -> bf16) ----------------
__global__ __launch_bounds__(256) void ln_tin_kernel(const float* __restrict__ f,
                                                     const float* __restrict__ g,
                                                     u16* __restrict__ xT) {
  __shared__ u16 tile[64 * 258];
  __shared__ float red[2 * 256];
  __shared__ float mu_s[64], inv_s[64];
  const int t = threadIdx.x;
  const int p0 = blockIdx.x * 64;
  const int b = blockIdx.y;
  const long fb = (long)b * 256 * 4096;
  const int p = t & 63, cg = t >> 6;
  float s1 = 0.f, s2 = 0.f;
  for (int pass = 0; pass < 64; ++pass) {
    int c = pass * 4 + cg;
    float v = f[fb + (long)c * 4096 + p0 + p];
    s1 += v; s2 += v * v;
    tile[p * 258 + c] = f2bf(v);
  }
  red[cg * 64 + p] = s1;
  red[256 + cg * 64 + p] = s2;
  __syncthreads();
  if (t < 64) {
    float a1 = red[t] + red[64 + t] + red[128 + t] + red[192 + t];
    float a2 = red[256 + t] + red[320 + t] + red[384 + t] + red[448 + t];
    float mu = a1 * (1.f / 256.f);
    float var = a2 * (1.f / 256.f) - mu * mu;
    mu_s[t] = mu;
    inv_s[t] = 1.0f / sqrtf(var + 1e-5f);
  }
  __syncthreads();
  {
    float gc = g[t];
    for (int pp = 0; pp < 64; ++pp) {
      float v = b2f(tile[pp * 258 + t]);
      xT[((long)b * 4096 + p0 + pp) * 256 + t] = f2bf((v - mu_s[pp]) * inv_s[pp] * gc);
    }
  }
}

// ---------------- GEMM: C[m][n] = sum_k A[m][k]*Bt[n][k] (MFMA 16x16x32, 128x128 tile) ----
__global__ __launch_bounds__(256) void gemm_bt_kernel(
    const u16* __restrict__ A, const u16* __restrict__ B0, const u16* __restrict__ B1,
    u16* __restrict__ Cg, int ldc, long sA, long sC) {
  __shared__ u16 As[128 * 32];
  __shared__ u16 Bs[128 * 32];
  const int t = threadIdx.x;
  const int wave = t >> 6, lane = t & 63, quad = lane >> 4, l16 = lane & 15;
  const int wr = wave >> 1, wc = wave & 1;
  const int m0 = blockIdx.x * 128;
  const int jt = blockIdx.y;
  const int b = blockIdx.z;
  const u16* Ab = A + (long)b * sA + (long)m0 * 256;
  const u16* Bt = (jt < 2 ? B0 : B1) + (jt & 1) * 128 * 256;
  u16* Cb = Cg + (long)b * sC + (long)m0 * ldc + jt * 128;

  const int srow = lane >> 2;        // staging: row within 16-row chunk
  const int scol = (lane & 3) * 8;   // staging: col (elements)
  f32x4 acc[4][4];
#pragma unroll
  for (int i = 0; i < 4; ++i)
#pragma unroll
    for (int j = 0; j < 4; ++j) acc[i][j] = (f32x4){0.f, 0.f, 0.f, 0.f};

  const int aoff = (wr * 64 + l16) * 32 + quad * 8;
  const int boff = (wc * 64 + l16) * 32 + quad * 8;

  for (int ks = 0; ks < 8; ++ks) {
    const int k0 = ks * 32;
    __syncthreads();
    for (int i = wave; i < 8; i += 4) {
      gl2lds16(Ab + (i * 16 + srow) * 256 + k0 + scol, &As[i * 512 + lane * 8]);
      gl2lds16(Bt + (i * 16 + srow) * 256 + k0 + scol, &Bs[i * 512 + lane * 8]);
    }
    __syncthreads();  // compiler drains vmcnt(0) before s_barrier
    bf16x8 af[4], bfr[4];
#pragma unroll
    for (int mt = 0; mt < 4; ++mt) af[mt] = *(const bf16x8*)&As[aoff + mt * 512];
#pragma unroll
    for (int nt = 0; nt < 4; ++nt) bfr[nt] = *(const bf16x8*)&Bs[boff + nt * 512];
#pragma unroll
    for (int mt = 0; mt < 4; ++mt)
#pragma unroll
      for (int nt = 0; nt < 4; ++nt)
        acc[mt][nt] = __builtin_amdgcn_mfma_f32_16x16x32_bf16(af[mt], bfr[nt], acc[mt][nt], 0, 0, 0);
  }
#pragma unroll
  for (int mt = 0; mt < 4; ++mt) {
    const int mbase = wr * 64 + mt * 16 + quad * 4;
#pragma unroll
    for (int nt = 0; nt < 4; ++nt) {
      const int n = wc * 64 + nt * 16 + l16;
#pragma unroll
      for (int r = 0; r < 4; ++r)
        Cb[(long)(mbase + r) * ldc + n] = f2bf(acc[mt][nt][r]);
    }
  }
}

// ---------------- K2: dwconv(q) + softmax over d + *SCALE (LDS-free row streamer) -------
// block = (strip of 16 x-rows, head, batch); lane owns (y = wave*16 + lane&15, 8 channels).
__global__ __launch_bounds__(256) void dwq_kernel(const u16* __restrict__ qT,
                                                  const float* __restrict__ wdw,
                                                  u16* __restrict__ qp) {
  const int t = threadIdx.x;
  const int strip = blockIdx.x, h = blockIdx.y, b = blockIdx.z;
  const int x0 = strip * 16;
  const int wave = t >> 6, lane = t & 63;
  const int ysel = lane & 15, cg = lane >> 4;
  const int y = wave * 16 + ysel;
  float w[72];
#pragma unroll
  for (int q = 0; q < 8; ++q)
#pragma unroll
    for (int i = 0; i < 9; ++i) w[q * 9 + i] = wdw[(h * 32 + cg * 8 + q) * 9 + i];
  const u16* qb = qT + (long)b * 4096 * 256 + h * 32 + cg * 8;
  u16* ob = qp + ((long)b * 4096 + y) * 256 + h * 32 + cg * 8;

  for (int x = x0; x < x0 + 16; ++x) {
    float acc[8] = {0.f, 0.f, 0.f, 0.f, 0.f, 0.f, 0.f, 0.f};
#pragma unroll
    for (int r = 0; r < 3; ++r) {
      const int xx = x - 1 + r;
#pragma unroll
      for (int dy = 0; dy < 3; ++dy) {
        const int yy = y - 1 + dy;
        if (((unsigned)xx < 64u) & ((unsigned)yy < 64u)) {
          uint4 pk = *(const uint4*)(qb + (long)(xx * 64 + yy) * 256);
          const u16* s = (const u16*)&pk;
#pragma unroll
          for (int q = 0; q < 8; ++q)
            acc[q] = fmaf(w[q * 9 + r * 3 + dy], b2f(s[q]), acc[q]);
        }
      }
    }
    float e[8];
    float s = 0.f;
#pragma unroll
    for (int q = 0; q < 8; ++q) { e[q] = __expf(acc[q]); s += e[q]; }
    s += __shfl_xor(s, 16);
    s += __shfl_xor(s, 32);
    const float inv = 0.17677669529663687f / s;  // SCALE / sum
    uint4 o;
    u16* os = (u16*)&o;
#pragma unroll
    for (int q = 0; q < 8; ++q) os[q] = f2bf(e[q] * inv);
    *(uint4*)(ob + (long)x * 16384) = o;
  }
}

// ---------------- K3: dwconv(k,v)+exp + Gram via 32x32x16 MFMA (register row streamer) --
// block = (strip of 16 x-rows, head, batch); lane owns channel c=lane&31, 8-y run.
__global__ __launch_bounds__(256) void ctx_kernel(const u16* __restrict__ kvT,
                                                  const float* __restrict__ wkdw,
                                                  const float* __restrict__ wvdw,
                                                  float* __restrict__ ctxg,
                                                  float* __restrict__ ksumg) {
  __shared__ float redb[3 * 1088];
  const int t = threadIdx.x;
  const int strip = blockIdx.x, h = blockIdx.y, b = blockIdx.z;
  const int x0 = strip * 16;
  const int wave = t >> 6, lane = t & 63;
  const int c = lane & 31, half = lane >> 5;
  const int ystart = wave * 16 + half * 8;
  float wk[9], wv[9];
#pragma unroll
  for (int i = 0; i < 9; ++i) {
    wk[i] = wkdw[(h * 32 + c) * 9 + i];
    wv[i] = wvdw[(h * 32 + c) * 9 + i];
  }
  const u16* kb = kvT + (long)b * 4096 * 512 + h * 32 + c;

  float fk[3][10], fv[3][10];
  // load rows x0-1, x0 into fk/fv[0], [1]
#pragma unroll
  for (int r = 0; r < 2; ++r) {
    const int x = x0 - 1 + r;
#pragma unroll
    for (int m = 0; m < 10; ++m) {
      const int yy = ystart - 1 + m;
      float a = 0.f, bb = 0.f;
      if (((unsigned)x < 64u) & ((unsigned)yy < 64u)) {
        const u16* p = kb + (long)(x * 64 + yy) * 512;
        a = b2f(p[0]);
        bb = b2f(p[256]);
      }
      fk[r][m] = a; fv[r][m] = bb;
    }
  }
  f32x16 acc;
#pragma unroll
  for (int r = 0; r < 16; ++r) acc[r] = 0.f;
  float ks = 0.f;

  for (int x = x0; x < x0 + 16; ++x) {
    // load row x+1 into slot 2
    {
      const int xn = x + 1;
#pragma unroll
      for (int m = 0; m < 10; ++m) {
        const int yy = ystart - 1 + m;
        float a = 0.f, bb = 0.f;
        if (((unsigned)xn < 64u) & ((unsigned)yy < 64u)) {
          const u16* p = kb + (long)(xn * 64 + yy) * 512;
          a = b2f(p[0]);
          bb = b2f(p[256]);
        }
        fk[2][m] = a; fv[2][m] = bb;
      }
    }
    // conv row x: outputs y = ystart..ystart+7
    union { bf16x8 v; u16 s[8]; } af, bf_;
#pragma unroll
    for (int j = 0; j < 8; ++j) {
      float a = 0.f, bb = 0.f;
#pragma unroll
      for (int r = 0; r < 3; ++r)
#pragma unroll
        for (int dy = 0; dy < 3; ++dy) {
          a = fmaf(wk[r * 3 + dy], fk[r][j + dy], a);
          bb = fmaf(wv[r * 3 + dy], fv[r][j + dy], bb);
        }
      const u16 eb = f2bf(__expf(a));
      ks += b2f(eb);
      af.s[j] = eb;
      bf_.s[j] = f2bf(bb);
    }
    acc = __builtin_amdgcn_mfma_f32_32x32x16_bf16(af.v, bf_.v, acc, 0, 0, 0);
    // roll rows
#pragma unroll
    for (int m = 0; m < 10; ++m) {
      fk[0][m] = fk[1][m]; fk[1][m] = fk[2][m];
      fv[0][m] = fv[1][m]; fv[1][m] = fv[2][m];
    }
  }
  // ksum: combine halves (same c), one atomic per channel per wave
  ks += __shfl_xor(ks, 32);
  if (half == 0) atomicAdd(&ksumg[((long)b * 8 + h) * 32 + c], ks);
  // ctx: reduce 4 waves in LDS, then wave 0 atomics
  if (wave > 0) {
#pragma unroll
    for (int r = 0; r < 16; ++r) redb[(wave - 1) * 1088 + lane * 17 + r] = acc[r];
  }
  __syncthreads();
  if (wave == 0) {
    float* cb = ctxg + ((long)b * 8 + h) * 1024;
#pragma unroll
    for (int r = 0; r < 16; ++r) {
      float sum = acc[r] + redb[lane * 17 + r] + redb[1088 + lane * 17 + r] +
                  redb[2176 + lane * 17 + r];
      const int d = (r & 3) + 8 * (r >> 2) + 4 * half;  // C/D row map [m74/m101]
      atomicAdd(&cb[d * 32 + c], sum);
    }
  }
}

// ---------------- K4: s = silu(q' @ (ctx/ksum)) ----------------
__global__ __launch_bounds__(256) void attn_kernel(const u16* __restrict__ qp,
                                                   const float* __restrict__ ctxg,
                                                   const float* __restrict__ ksumg,
                                                   u16* __restrict__ sout) {
  __shared__ float ctxn[8192];
  __shared__ u16 qlds[64 * 40];
  const int t = threadIdx.x;
  const int p0 = blockIdx.x * 64;
  const int b = blockIdx.y;
  for (int i = 0; i < 32; ++i) {
    int idx = i * 256 + t;
    ctxn[idx] = ctxg[(long)b * 8192 + idx] / ksumg[(long)b * 256 + (idx >> 5)];
  }
  __syncthreads();
  const int e = t & 31, pg = t >> 5;
  const int lr = t >> 2, lc = t & 3;
  float cc[32];
  for (int h = 0; h < 8; ++h) {
    __syncthreads();
    *(uint4*)&qlds[lr * 40 + lc * 8] =
        *(const uint4*)&qp[((long)b * 4096 + p0 + lr) * 256 + h * 32 + lc * 8];
#pragma unroll
    for (int d = 0; d < 32; ++d) cc[d] = ctxn[(h * 32 + d) * 32 + e];
    __syncthreads();
    for (int k = 0; k < 8; ++k) {
      int p = pg + k * 8;
      float a = 0.f;
#pragma unroll
      for (int jq = 0; jq < 4; ++jq) {
        bf16x8 qv = *(const bf16x8*)&qlds[p * 40 + jq * 8];
#pragma unroll
        for (int jj = 0; jj < 8; ++jj) a = fmaf((float)qv[jj], cc[jq * 8 + jj], a);
      }
      float sl = a / (1.f + __expf(-a));  // silu
      sout[((long)b * 4096 + p0 + p) * 256 + h * 32 + e] = f2bf(sl);
    }
  }
}

// ---------------- K6: channel-LN + transpose out (bf16 -> fp32) ----------------
__global__ __launch_bounds__(256) void ln_tout_kernel(const u16* __restrict__ y,
                                                      const float* __restrict__ gout,
                                                      float* __restrict__ out) {
  __shared__ u16 tile[64 * 258];
  __shared__ float red[2 * 256];
  __shared__ float mu_s[64], inv_s[64];
  const int t = threadIdx.x;
  const int p0 = blockIdx.x * 64;
  const int b = blockIdx.y;
  for (int p = 0; p < 64; ++p)
    tile[p * 258 + t] = y[((long)b * 4096 + p0 + p) * 256 + t];
  __syncthreads();
  {
    const int p = t & 63, part = t >> 6;
    float s1 = 0.f, s2 = 0.f;
    for (int k = 0; k < 64; ++k) {
      float v = b2f(tile[p * 258 + part * 64 + k]);
      s1 += v; s2 += v * v;
    }
    red[part * 64 + p] = s1;
    red[256 + part * 64 + p] = s2;
  }
  __syncthreads();
  if (t < 64) {
    float s1 = red[t] + red[64 + t] + red[128 + t] + red[192 + t];
    float s2 = red[256 + t] + red[320 + t] + red[384 + t] + red[448 + t];
    float mu = s1 * (1.f / 256.f);
    float var = s2 * (1.f / 256.f) - mu * mu;
    mu_s[t] = mu;
    inv_s[t] = 1.0f / sqrtf(var + 1e-5f);
  }
  __syncthreads();
  {
    const int p = t & 63, cg = t >> 6;
    const long ob = (long)b * 256 * 4096;
    for (int pass = 0; pass < 64; ++pass) {
      int c = pass * 4 + cg;
      float v = b2f(tile[p * 258 + c]);
      out[ob + (long)c * 4096 + p0 + p] = (v - mu_s[p]) * inv_s[p] * gout[c];
    }
  }
}

extern "C" void kernel_launch(void* const* d_in, const int* in_sizes, int n_in,
                              void* d_out, int out_size, void* d_ws, size_t ws_size,
                              hipStream_t stream) {
  (void)in_sizes; (void)n_in; (void)out_size; (void)ws_size;
  const float* fmap = (const float*)d_in[0];
  const float* gnorm = (const float*)d_in[1];
  const float* wq1 = (const float*)d_in[2];
  const float* wqdw = (const float*)d_in[3];
  const float* wk1 = (const float*)d_in[4];
  const float* wkdw = (const float*)d_in[5];
  const float* wv1 = (const float*)d_in[6];
  const float* wvdw = (const float*)d_in[7];
  const float* wo = (const float*)d_in[8];
  const float* gout = (const float*)d_in[9];
  float* out = (float*)d_out;
  char* ws = (char*)d_ws;

  float* ctxg = (float*)(ws);                    // [0, 512K)
  float* ksumg = (float*)(ws + 524288);          // [512K, 528K)
  u16* wb = (u16*)(ws + 540672);                 // [528K, 1040K) bf16 wk|wv|wq|wo
  u16* wk_bf = wb;
  u16* wv_bf = wb + 65536;
  u16* wq_bf = wb + 131072;
  u16* wo_bf = wb + 196608;
  u16* xT = (u16*)(ws + 2097152);                // [2, 34) MiB
  u16* kvT = (u16*)(ws + 35651584);              // [34, 98) MiB
  u16* qT = kvT;                                 // alias (kvT dead after ctx)
  u16* qp = (u16*)(ws + 69206016);               // [66, 98) MiB
  u16* sbuf = xT;                                // alias (xT dead after Q gemm)
  u16* ybuf = qp;                                // alias (qp dead after attn)

  hipMemsetAsync(ws, 0, 540672, stream);
  prep_kernel<<<dim3(256, 4), 256, 0, stream>>>(wk1, wv1, wq1, wo, wb);
  ln_tin_kernel<<<dim3(64, 16), 256, 0, stream>>>(fmap, gnorm, xT);
  // KV: cols 0..255 = x@wk1^T, cols 256..511 = x@wv1^T
  gemm_bt_kernel<<<dim3(32, 4, 16), 256, 0, stream>>>(xT, wk_bf, wv_bf, kvT, 512,
                                                      4096L * 256, 4096L * 512);
  ctx_kernel<<<dim3(4, 8, 16), 256, 0, stream>>>(kvT, wkdw, wvdw, ctxg, ksumg);
  // Q
  gemm_bt_kernel<<<dim3(32, 2, 16), 256, 0, stream>>>(xT, wq_bf, wq_bf, qT, 256,
                                                      4096L * 256, 4096L * 256);
  dwq_kernel<<<dim3(4, 8, 16), 256, 0, stream>>>(qT, wqdw, qp);
  attn_kernel<<<dim3(64, 16), 256, 0, stream>>>(qp, ctxg, ksumg, sbuf);
  // O
  gemm_bt_kernel<<<dim3(32, 2, 16), 256, 0, stream>>>(sbuf, wo_bf, wo_bf, ybuf, 256,
                                                      4096L * 256, 4096L * 256);
  ln_tout_kernel<<<dim3(64, 16), 256, 0, stream>>>(ybuf, gout, out);
}

// Round 6
// 379.596 us; speedup vs baseline: 1.2388x; 1.0035x over previous
//
#include <hip/hip_runtime.h>

// LinearAttention (B=16, C=256, 64x64 spatial, 8 heads x 32) -- fp32 in/out, bf16/fp32 internal.
// Workspace map (byte offsets), peak 98 MiB:
//   ctxg  [0, 512K)              fp32 [16][8][32][32]  (atomic accumulators, memset 0)
//   ksumg [512K, 528K)           fp32 [16][8][32]
//   wb    [528K, 1040K)          bf16 weights: wk|wv|wq|wo (4 x 65536 elems)
//   xT    [2 MiB, 34 MiB)        bf16 [16][4096][256]   LN(fmap)*g, transposed
//   kvT   [34 MiB, 98 MiB)       bf16 [16][4096][512]   LIVE during ctx -- nothing may alias it then!
//   qT    [34 MiB, 66 MiB)       alias (kvT dead after ctx)
//   q'    [66 MiB, 98 MiB)       softmaxed q
//   s     [2 MiB, 34 MiB)        silu(attn out)  (xT dead)
//   y     [66 MiB, 98 MiB)       s @ wo^T        (q' dead)
// Order: memset -> prep -> ln_tin -> gemm(KV) -> ctx -> gemm(Q) -> dwq -> attn -> gemm(O) -> ln_tout

typedef unsigned short u16;
typedef __bf16 bf16x8 __attribute__((ext_vector_type(8)));
typedef float f32x4 __attribute__((ext_vector_type(4)));
typedef float f32x16 __attribute__((ext_vector_type(16)));

#define DEV static __device__ __forceinline__

DEV float b2f(u16 u) { return __uint_as_float(((unsigned int)u) << 16); }
DEV u16 f2bf(float f) {
  unsigned int u = __float_as_uint(f);
  return (u16)((u + 0x7fffu + ((u >> 16) & 1u)) >> 16);  // RNE
}
DEV void gl2lds16(const void* g, void* l) {
  __builtin_amdgcn_global_load_lds((__attribute__((address_space(1))) void*)g,
                                   (__attribute__((address_space(3))) void*)l, 16, 0, 0);
}

// ---------------- prep: fp32 -> bf16 weight conversion ----------------
__global__ __launch_bounds__(256) void prep_kernel(const float* __restrict__ wk,
                                                   const float* __restrict__ wv,
                                                   const float* __restrict__ wq,
                                                   const float* __restrict__ wo,
                                                   u16* __restrict__ wb) {
  const int i = blockIdx.x * 256 + threadIdx.x;  // 0..65535
  const float* src = (blockIdx.y == 0) ? wk : (blockIdx.y == 1) ? wv : (blockIdx.y == 2) ? wq : wo;
  wb[blockIdx.y * 65536 + i] = f2bf(src[i]);
}

// ---------------- K0: channel-LN + transpose in (fp32 -> bf16) ----------------
__global__ __launch_bounds__(256) void ln_tin_kernel(const float* __restrict__ f,
                                                     const float* __restrict__ g,
                                                     u16* __restrict__ xT) {
  __shared__ u16 tile[64 * 258];
  __shared__ float red[2 * 256];
  __shared__ float mu_s[64], inv_s[64];
  const int t = threadIdx.x;
  const int p0 = blockIdx.x * 64;
  const int b = blockIdx.y;
  const long fb = (long)b * 256 * 4096;
  const int p = t & 63, cg = t >> 6;
  float s1 = 0.f, s2 = 0.f;
  for (int pass = 0; pass < 64; ++pass) {
    int c = pass * 4 + cg;
    float v = f[fb + (long)c * 4096 + p0 + p];
    s1 += v; s2 += v * v;
    tile[p * 258 + c] = f2bf(v);
  }
  red[cg * 64 + p] = s1;
  red[256 + cg * 64 + p] = s2;
  __syncthreads();
  if (t < 64) {
    float a1 = red[t] + red[64 + t] + red[128 + t] + red[192 + t];
    float a2 = red[256 + t] + red[320 + t] + red[384 + t] + red[448 + t];
    float mu = a1 * (1.f / 256.f);
    float var = a2 * (1.f / 256.f) - mu * mu;
    mu_s[t] = mu;
    inv_s[t] = 1.0f / sqrtf(var + 1e-5f);
  }
  __syncthreads();
  {
    float gc = g[t];
    for (int pp = 0; pp < 64; ++pp) {
      float v = b2f(tile[pp * 258 + t]);
      xT[((long)b * 4096 + p0 + pp) * 256 + t] = f2bf((v - mu_s[pp]) * inv_s[pp] * gc);
    }
  }
}

// ---------------- GEMM: C[m][n] = sum_k A[m][k]*Bt[n][k] (MFMA 16x16x32, 128x128 tile) ----
__global__ __launch_bounds__(256) void gemm_bt_kernel(
    const u16* __restrict__ A, const u16* __restrict__ B0, const u16* __restrict__ B1,
    u16* __restrict__ Cg, int ldc, long sA, long sC) {
  __shared__ u16 As[128 * 32];
  __shared__ u16 Bs[128 * 32];
  const int t = threadIdx.x;
  const int wave = t >> 6, lane = t & 63, quad = lane >> 4, l16 = lane & 15;
  const int wr = wave >> 1, wc = wave & 1;
  const int m0 = blockIdx.x * 128;
  const int jt = blockIdx.y;
  const int b = blockIdx.z;
  const u16* Ab = A + (long)b * sA + (long)m0 * 256;
  const u16* Bt = (jt < 2 ? B0 : B1) + (jt & 1) * 128 * 256;
  u16* Cb = Cg + (long)b * sC + (long)m0 * ldc + jt * 128;

  const int srow = lane >> 2;        // staging: row within 16-row chunk
  const int scol = (lane & 3) * 8;   // staging: col (elements)
  f32x4 acc[4][4];
#pragma unroll
  for (int i = 0; i < 4; ++i)
#pragma unroll
    for (int j = 0; j < 4; ++j) acc[i][j] = (f32x4){0.f, 0.f, 0.f, 0.f};

  const int aoff = (wr * 64 + l16) * 32 + quad * 8;
  const int boff = (wc * 64 + l16) * 32 + quad * 8;

  for (int ks = 0; ks < 8; ++ks) {
    const int k0 = ks * 32;
    __syncthreads();
    for (int i = wave; i < 8; i += 4) {
      gl2lds16(Ab + (i * 16 + srow) * 256 + k0 + scol, &As[i * 512 + lane * 8]);
      gl2lds16(Bt + (i * 16 + srow) * 256 + k0 + scol, &Bs[i * 512 + lane * 8]);
    }
    __syncthreads();  // compiler drains vmcnt(0) before s_barrier
    bf16x8 af[4], bfr[4];
#pragma unroll
    for (int mt = 0; mt < 4; ++mt) af[mt] = *(const bf16x8*)&As[aoff + mt * 512];
#pragma unroll
    for (int nt = 0; nt < 4; ++nt) bfr[nt] = *(const bf16x8*)&Bs[boff + nt * 512];
#pragma unroll
    for (int mt = 0; mt < 4; ++mt)
#pragma unroll
      for (int nt = 0; nt < 4; ++nt)
        acc[mt][nt] = __builtin_amdgcn_mfma_f32_16x16x32_bf16(af[mt], bfr[nt], acc[mt][nt], 0, 0, 0);
  }
#pragma unroll
  for (int mt = 0; mt < 4; ++mt) {
    const int mbase = wr * 64 + mt * 16 + quad * 4;
#pragma unroll
    for (int nt = 0; nt < 4; ++nt) {
      const int n = wc * 64 + nt * 16 + l16;
#pragma unroll
      for (int r = 0; r < 4; ++r)
        Cb[(long)(mbase + r) * ldc + n] = f2bf(acc[mt][nt][r]);
    }
  }
}

// ---------------- K2: dwconv(q) + softmax over d + *SCALE (LDS-free row streamer) -------
// block = (strip of 4 x-rows, head, batch); lane owns (y = wave*16 + lane&15, 8 channels).
__global__ __launch_bounds__(256) void dwq_kernel(const u16* __restrict__ qT,
                                                  const float* __restrict__ wdw,
                                                  u16* __restrict__ qp) {
  const int t = threadIdx.x;
  const int strip = blockIdx.x, h = blockIdx.y, b = blockIdx.z;
  const int x0 = strip * 4;
  const int wave = t >> 6, lane = t & 63;
  const int ysel = lane & 15, cg = lane >> 4;
  const int y = wave * 16 + ysel;
  float w[72];
#pragma unroll
  for (int q = 0; q < 8; ++q)
#pragma unroll
    for (int i = 0; i < 9; ++i) w[q * 9 + i] = wdw[(h * 32 + cg * 8 + q) * 9 + i];
  const u16* qb = qT + (long)b * 4096 * 256 + h * 32 + cg * 8;
  u16* ob = qp + ((long)b * 4096 + y) * 256 + h * 32 + cg * 8;

#pragma unroll
  for (int it = 0; it < 4; ++it) {
    const int x = x0 + it;
    float acc[8] = {0.f, 0.f, 0.f, 0.f, 0.f, 0.f, 0.f, 0.f};
#pragma unroll
    for (int r = 0; r < 3; ++r) {
      const int xx = x - 1 + r;
#pragma unroll
      for (int dy = 0; dy < 3; ++dy) {
        const int yy = y - 1 + dy;
        if (((unsigned)xx < 64u) & ((unsigned)yy < 64u)) {
          uint4 pk = *(const uint4*)(qb + (long)(xx * 64 + yy) * 256);
          const u16* s = (const u16*)&pk;
#pragma unroll
          for (int q = 0; q < 8; ++q)
            acc[q] = fmaf(w[q * 9 + r * 3 + dy], b2f(s[q]), acc[q]);
        }
      }
    }
    float e[8];
    float s = 0.f;
#pragma unroll
    for (int q = 0; q < 8; ++q) { e[q] = __expf(acc[q]); s += e[q]; }
    s += __shfl_xor(s, 16);
    s += __shfl_xor(s, 32);
    const float inv = 0.17677669529663687f / s;  // SCALE / sum
    uint4 o;
    u16* os = (u16*)&o;
#pragma unroll
    for (int q = 0; q < 8; ++q) os[q] = f2bf(e[q] * inv);
    *(uint4*)(ob + (long)x * 16384) = o;
  }
}

// ---------------- K3: dwconv(k,v)+exp + Gram via 32x32x16 MFMA (register row streamer) --
// block = (strip of 4 x-rows, head, batch); lane owns channel c=lane&31, 8-y run.
// LDS cross-wave reduce, then wave 0 atomicAdd into ctxg/ksumg (zeroed by memset).
__global__ __launch_bounds__(256, 4) void ctx_kernel(const u16* __restrict__ kvT,
                                                     const float* __restrict__ wkdw,
                                                     const float* __restrict__ wvdw,
                                                     float* __restrict__ ctxg,
                                                     float* __restrict__ ksumg) {
  __shared__ float redb[3 * 1088];
  __shared__ float redk[128];
  const int t = threadIdx.x;
  const int strip = blockIdx.x, h = blockIdx.y, b = blockIdx.z;
  const int x0 = strip * 4;
  const int wave = t >> 6, lane = t & 63;
  const int c = lane & 31, half = lane >> 5;
  const int ystart = wave * 16 + half * 8;
  float wk[9], wv[9];
#pragma unroll
  for (int i = 0; i < 9; ++i) {
    wk[i] = wkdw[(h * 32 + c) * 9 + i];
    wv[i] = wvdw[(h * 32 + c) * 9 + i];
  }
  const u16* kb = kvT + (long)b * 4096 * 512 + h * 32 + c;

  float fk[3][10], fv[3][10];
#pragma unroll
  for (int r = 0; r < 2; ++r) {
    const int x = x0 - 1 + r;
#pragma unroll
    for (int m = 0; m < 10; ++m) {
      const int yy = ystart - 1 + m;
      float a = 0.f, bb = 0.f;
      if (((unsigned)x < 64u) & ((unsigned)yy < 64u)) {
        const u16* p = kb + (long)(x * 64 + yy) * 512;
        a = b2f(p[0]);
        bb = b2f(p[256]);
      }
      fk[r][m] = a; fv[r][m] = bb;
    }
  }
  f32x16 acc;
#pragma unroll
  for (int r = 0; r < 16; ++r) acc[r] = 0.f;
  float ks = 0.f;

#pragma unroll
  for (int it = 0; it < 4; ++it) {
    const int x = x0 + it;
    {
      const int xn = x + 1;
#pragma unroll
      for (int m = 0; m < 10; ++m) {
        const int yy = ystart - 1 + m;
        float a = 0.f, bb = 0.f;
        if (((unsigned)xn < 64u) & ((unsigned)yy < 64u)) {
          const u16* p = kb + (long)(xn * 64 + yy) * 512;
          a = b2f(p[0]);
          bb = b2f(p[256]);
        }
        fk[2][m] = a; fv[2][m] = bb;
      }
    }
    union { bf16x8 v; u16 s[8]; } af, bf_;
#pragma unroll
    for (int j = 0; j < 8; ++j) {
      float a = 0.f, bb = 0.f;
#pragma unroll
      for (int r = 0; r < 3; ++r)
#pragma unroll
        for (int dy = 0; dy < 3; ++dy) {
          a = fmaf(wk[r * 3 + dy], fk[r][j + dy], a);
          bb = fmaf(wv[r * 3 + dy], fv[r][j + dy], bb);
        }
      const u16 eb = f2bf(__expf(a));
      ks += b2f(eb);
      af.s[j] = eb;
      bf_.s[j] = f2bf(bb);
    }
    acc = __builtin_amdgcn_mfma_f32_32x32x16_bf16(af.v, bf_.v, acc, 0, 0, 0);
#pragma unroll
    for (int m = 0; m < 10; ++m) {
      fk[0][m] = fk[1][m]; fk[1][m] = fk[2][m];
      fv[0][m] = fv[1][m]; fv[1][m] = fv[2][m];
    }
  }
  // ksum: combine halves (same c), stage per-wave in LDS
  ks += __shfl_xor(ks, 32);
  if (half == 0) redk[wave * 32 + c] = ks;
  // ctx: waves 1-3 stage in LDS
  if (wave > 0) {
#pragma unroll
    for (int r = 0; r < 16; ++r) redb[(wave - 1) * 1088 + lane * 17 + r] = acc[r];
  }
  __syncthreads();
  if (wave == 0) {
    float* cb = ctxg + ((long)(b * 8 + h)) * 1024;
#pragma unroll
    for (int r = 0; r < 16; ++r) {
      float sum = acc[r] + redb[lane * 17 + r] + redb[1088 + lane * 17 + r] +
                  redb[2176 + lane * 17 + r];
      const int d = (r & 3) + 8 * (r >> 2) + 4 * half;  // C/D row map [m74/m101]
      atomicAdd(&cb[d * 32 + c], sum);
    }
    if (t < 32)
      atomicAdd(&ksumg[((long)(b * 8 + h)) * 32 + t],
                redk[t] + redk[32 + t] + redk[64 + t] + redk[96 + t]);
  }
}

// ---------------- K4: s = silu(q' @ (ctx/ksum)) ----------------
__global__ __launch_bounds__(256) void attn_kernel(const u16* __restrict__ qp,
                                                   const float* __restrict__ ctxg,
                                                   const float* __restrict__ ksumg,
                                                   u16* __restrict__ sout) {
  __shared__ float ctxn[8192];
  __shared__ u16 qlds[64 * 40];
  const int t = threadIdx.x;
  const int p0 = blockIdx.x * 64;
  const int b = blockIdx.y;
  for (int i = 0; i < 32; ++i) {
    int idx = i * 256 + t;
    ctxn[idx] = ctxg[(long)b * 8192 + idx] / ksumg[(long)b * 256 + (idx >> 5)];
  }
  __syncthreads();
  const int e = t & 31, pg = t >> 5;
  const int lr = t >> 2, lc = t & 3;
  float cc[32];
  for (int h = 0; h < 8; ++h) {
    __syncthreads();
    *(uint4*)&qlds[lr * 40 + lc * 8] =
        *(const uint4*)&qp[((long)b * 4096 + p0 + lr) * 256 + h * 32 + lc * 8];
#pragma unroll
    for (int d = 0; d < 32; ++d) cc[d] = ctxn[(h * 32 + d) * 32 + e];
    __syncthreads();
    for (int k = 0; k < 8; ++k) {
      int p = pg + k * 8;
      float a = 0.f;
#pragma unroll
      for (int jq = 0; jq < 4; ++jq) {
        bf16x8 qv = *(const bf16x8*)&qlds[p * 40 + jq * 8];
#pragma unroll
        for (int jj = 0; jj < 8; ++jj) a = fmaf((float)qv[jj], cc[jq * 8 + jj], a);
      }
      float sl = a / (1.f + __expf(-a));  // silu
      sout[((long)b * 4096 + p0 + p) * 256 + h * 32 + e] = f2bf(sl);
    }
  }
}

// ---------------- K6: channel-LN + transpose out (bf16 -> fp32) ----------------
__global__ __launch_bounds__(256) void ln_tout_kernel(const u16* __restrict__ y,
                                                      const float* __restrict__ gout,
                                                      float* __restrict__ out) {
  __shared__ u16 tile[64 * 258];
  __shared__ float red[2 * 256];
  __shared__ float mu_s[64], inv_s[64];
  const int t = threadIdx.x;
  const int p0 = blockIdx.x * 64;
  const int b = blockIdx.y;
  for (int p = 0; p < 64; ++p)
    tile[p * 258 + t] = y[((long)b * 4096 + p0 + p) * 256 + t];
  __syncthreads();
  {
    const int p = t & 63, part = t >> 6;
    float s1 = 0.f, s2 = 0.f;
    for (int k = 0; k < 64; ++k) {
      float v = b2f(tile[p * 258 + part * 64 + k]);
      s1 += v; s2 += v * v;
    }
    red[part * 64 + p] = s1;
    red[256 + part * 64 + p] = s2;
  }
  __syncthreads();
  if (t < 64) {
    float s1 = red[t] + red[64 + t] + red[128 + t] + red[192 + t];
    float s2 = red[256 + t] + red[320 + t] + red[384 + t] + red[448 + t];
    float mu = s1 * (1.f / 256.f);
    float var = s2 * (1.f / 256.f) - mu * mu;
    mu_s[t] = mu;
    inv_s[t] = 1.0f / sqrtf(var + 1e-5f);
  }
  __syncthreads();
  {
    const int p = t & 63, cg = t >> 6;
    const long ob = (long)b * 256 * 4096;
    for (int pass = 0; pass < 64; ++pass) {
      int c = pass * 4 + cg;
      float v = b2f(tile[p * 258 + c]);
      out[ob + (long)c * 4096 + p0 + p] = (v - mu_s[p]) * inv_s[p] * gout[c];
    }
  }
}

extern "C" void kernel_launch(void* const* d_in, const int* in_sizes, int n_in,
                              void* d_out, int out_size, void* d_ws, size_t ws_size,
                              hipStream_t stream) {
  (void)in_sizes; (void)n_in; (void)out_size; (void)ws_size;
  const float* fmap = (const float*)d_in[0];
  const float* gnorm = (const float*)d_in[1];
  const float* wq1 = (const float*)d_in[2];
  const float* wqdw = (const float*)d_in[3];
  const float* wk1 = (const float*)d_in[4];
  const float* wkdw = (const float*)d_in[5];
  const float* wv1 = (const float*)d_in[6];
  const float* wvdw = (const float*)d_in[7];
  const float* wo = (const float*)d_in[8];
  const float* gout = (const float*)d_in[9];
  float* out = (float*)d_out;
  char* ws = (char*)d_ws;

  float* ctxg = (float*)(ws);                    // [0, 512K)
  float* ksumg = (float*)(ws + 524288);          // [512K, 528K)
  u16* wb = (u16*)(ws + 540672);                 // [528K, 1040K) bf16 wk|wv|wq|wo
  u16* wk_bf = wb;
  u16* wv_bf = wb + 65536;
  u16* wq_bf = wb + 131072;
  u16* wo_bf = wb + 196608;
  u16* xT = (u16*)(ws + 2097152);                // [2, 34) MiB
  u16* kvT = (u16*)(ws + 35651584);              // [34, 98) MiB -- live through ctx
  u16* qT = kvT;                                 // alias (kvT dead after ctx)
  u16* qp = (u16*)(ws + 69206016);               // [66, 98) MiB (written only after ctx)
  u16* sbuf = xT;                                // alias (xT dead after Q gemm)
  u16* ybuf = qp;                                // alias (qp dead after attn)

  hipMemsetAsync(ws, 0, 540672, stream);
  prep_kernel<<<dim3(256, 4), 256, 0, stream>>>(wk1, wv1, wq1, wo, wb);
  ln_tin_kernel<<<dim3(64, 16), 256, 0, stream>>>(fmap, gnorm, xT);
  // KV: cols 0..255 = x@wk1^T, cols 256..511 = x@wv1^T
  gemm_bt_kernel<<<dim3(32, 4, 16), 256, 0, stream>>>(xT, wk_bf, wv_bf, kvT, 512,
                                                      4096L * 256, 4096L * 512);
  ctx_kernel<<<dim3(16, 8, 16), 256, 0, stream>>>(kvT, wkdw, wvdw, ctxg, ksumg);
  // Q
  gemm_bt_kernel<<<dim3(32, 2, 16), 256, 0, stream>>>(xT, wq_bf, wq_bf, qT, 256,
                                                      4096L * 256, 4096L * 256);
  dwq_kernel<<<dim3(16, 8, 16), 256, 0, stream>>>(qT, wqdw, qp);
  attn_kernel<<<dim3(64, 16), 256, 0, stream>>>(qp, ctxg, ksumg, sbuf);
  // O
  gemm_bt_kernel<<<dim3(32, 2, 16), 256, 0, stream>>>(sbuf, wo_bf, wo_bf, ybuf, 256,
                                                      4096L * 256, 4096L * 256);
  ln_tout_kernel<<<dim3(64, 16), 256, 0, stream>>>(ybuf, gout, out);
}